// Round 8
// baseline (310.028 us; speedup 1.0000x reference)
//
#include <hip/hip_runtime.h>
#include <math.h>

#define NN 50000
#define EE 800000
#define FIN 96
#define FHID 384
#define FOUT 192
#define BN_EPS 1e-5f
#define NBLK_SCAN 196   // ceil(NN/256)
#define NBUCKET 391     // ceil(NN/128), bucket = row >> 7
#define NCHUNK 391      // ceil(EE/2048)

typedef short  short4v  __attribute__((ext_vector_type(4)));
typedef short  short8v  __attribute__((ext_vector_type(8)));
typedef float  f32x4    __attribute__((ext_vector_type(4)));

__device__ __forceinline__ unsigned short f2b(float f) {   // fp32 -> bf16 RNE
    unsigned u = __float_as_uint(f);
    unsigned r = u + 0x7FFFu + ((u >> 16) & 1u);
    return (unsigned short)(r >> 16);
}
__device__ __forceinline__ float b2f(unsigned short s) {
    return __uint_as_float((unsigned)s << 16);
}

// ---------------- prep: weights bf16+transpose, x -> bf16 -----------------
__global__ __launch_bounds__(256) void prep_kernel(
    const float* __restrict__ W1, const float* __restrict__ W2,
    const float* __restrict__ x,
    unsigned short* __restrict__ W1T, unsigned short* __restrict__ W2T,
    unsigned short* __restrict__ xb)
{
    int gid = blockIdx.x * 256 + threadIdx.x;
    if (gid < FHID * FIN) {                 // W1T[n][k] = W1[k][n]
        int n = gid / FIN, k = gid - n * FIN;
        W1T[gid] = f2b(W1[(size_t)k * FHID + n]);
        return;
    }
    int j = gid - FHID * FIN;
    if (j < FOUT * FHID) {                  // W2T[n][k] = W2[k][n]
        int n = j / FHID, k = j - n * FHID;
        W2T[j] = f2b(W2[(size_t)k * FOUT + n]);
        return;
    }
    int i4 = gid - FHID * FIN - FOUT * FHID;
    if (i4 < NN * FIN / 4) {
        float4 v = *(const float4*)(x + (size_t)i4 * 4);
        short4v s;
        s.x = f2b(v.x); s.y = f2b(v.y); s.z = f2b(v.z); s.w = f2b(v.w);
        *(short4v*)(xb + (size_t)i4 * 4) = s;
    }
}

// ---------------- row-level CSR: hist + scan ------------------------------
__global__ __launch_bounds__(256) void hist_kernel(
    const int* __restrict__ row, int* __restrict__ deg)
{
    int i = blockIdx.x * 256 + threadIdx.x;
    if (i < EE) atomicAdd(&deg[row[i]], 1);
}

__global__ __launch_bounds__(256) void scan_partial_kernel(
    const int* __restrict__ deg, int* __restrict__ bsum)
{
    __shared__ int s[256];
    int t = threadIdx.x;
    int i = blockIdx.x * 256 + t;
    s[t] = (i < NN) ? deg[i] : 0;
    __syncthreads();
    #pragma unroll
    for (int o = 128; o > 0; o >>= 1) {
        if (t < o) s[t] += s[t + o];
        __syncthreads();
    }
    if (t == 0) bsum[blockIdx.x] = s[0];
}

__global__ __launch_bounds__(256) void scan_tot_kernel(
    int* __restrict__ bsum, int* __restrict__ offsets)
{
    __shared__ int s[256];
    int t = threadIdx.x;
    int v = (t < NBLK_SCAN) ? bsum[t] : 0;
    s[t] = v;
    __syncthreads();
    for (int o = 1; o < 256; o <<= 1) {
        int add = (t >= o) ? s[t - o] : 0;
        __syncthreads();
        s[t] += add;
        __syncthreads();
    }
    if (t < NBLK_SCAN) bsum[t] = s[t] - v;
    if (t == 255) offsets[NN] = s[255];
}

// offs[i] = exclusive scan; also bcur[b] = offs[128b] for the bin pass
__global__ __launch_bounds__(256) void scan_final_kernel(
    const int* __restrict__ deg, const int* __restrict__ bsum,
    int* __restrict__ offsets, int* __restrict__ bcur)
{
    __shared__ int s[256];
    int t = threadIdx.x;
    int i = blockIdx.x * 256 + t;
    int v = (i < NN) ? deg[i] : 0;
    s[t] = v;
    __syncthreads();
    for (int o = 1; o < 256; o <<= 1) {
        int add = (t >= o) ? s[t - o] : 0;
        __syncthreads();
        s[t] += add;
        __syncthreads();
    }
    int excl = s[t] - v + bsum[blockIdx.x];
    if (i < NN) {
        offsets[i] = excl;
        if ((i & 127) == 0) bcur[i >> 7] = excl;
    }
}

// ---------------- pass 1: bin edges by bucket (coalesced-run writes) ------
__global__ __launch_bounds__(256) void bucket_bin_kernel(
    const int* __restrict__ row, const int* __restrict__ col,
    const float* __restrict__ val, int* __restrict__ bcur,
    int2* __restrict__ ebin)
{
    __shared__ int lh[NBUCKET];
    __shared__ int lg[NBUCKET];
    int tid = threadIdx.x;
    for (int i = tid; i < NBUCKET; i += 256) lh[i] = 0;
    __syncthreads();
    int base = blockIdx.x * 2048;
    int eb[8], er[8], ec[8], ev[8];
    #pragma unroll
    for (int j = 0; j < 8; ++j) {
        int e = base + j * 256 + tid;
        eb[j] = -1;
        if (e < EE) {
            int r = row[e];
            int b = r >> 7;
            eb[j] = b;
            er[j] = atomicAdd(&lh[b], 1);              // local rank
            ec[j] = col[e] | ((r & 127) << 17);        // col(17b) | rowlocal(7b)
            ev[j] = __float_as_int(val[e]);
        }
    }
    __syncthreads();
    for (int i = tid; i < NBUCKET; i += 256)
        if (lh[i]) lg[i] = atomicAdd(&bcur[i], lh[i]);
    __syncthreads();
    #pragma unroll
    for (int j = 0; j < 8; ++j) {
        if (eb[j] >= 0)
            ebin[lg[eb[j]] + er[j]] = make_int2(ec[j], ev[j]);
    }
}

// ---------------- pass 2: row-sort within bucket (16 KB window writes) ----
__global__ __launch_bounds__(256) void rebin_kernel(
    const int* __restrict__ offs, const int2* __restrict__ ebin,
    int2* __restrict__ epack)
{
    __shared__ int lcur[128];
    int b = blockIdx.x;
    int tid = threadIdx.x;
    int rbase = b * 128;
    if (tid < 128) {
        int r = rbase + tid;
        lcur[tid] = (r < NN) ? offs[r] : 0;
    }
    __syncthreads();
    int beg = offs[rbase];
    int end = offs[min(rbase + 128, NN)];
    for (int e = beg + tid; e < end; e += 256) {
        int2 ed = ebin[e];
        int rl = ed.x >> 17;
        int p = atomicAdd(&lcur[rl], 1);
        epack[p] = make_int2(ed.x & 0x1FFFF, ed.y);
    }
}

// ---------------- gather-aggregate (row CSR, bf16 x) -> bf16 agg ----------
__global__ __launch_bounds__(256) void gather_kernel(
    const unsigned short* __restrict__ xb, const int* __restrict__ offsets,
    const int2* __restrict__ epack, const float* __restrict__ epsp,
    unsigned short* __restrict__ aggb)
{
    int rid = blockIdx.x * 8 + (threadIdx.x >> 5);
    if (rid >= NN) return;
    int lane = threadIdx.x & 31;
    int beg = offsets[rid], end = offsets[rid + 1];
    float a0 = 0.f, a1 = 0.f, a2 = 0.f;
    int j = beg;
    for (; j + 4 <= end; j += 4) {
        int2 e0 = epack[j],   e1 = epack[j+1];
        int2 e2 = epack[j+2], e3 = epack[j+3];
        const unsigned short* x0 = xb + (size_t)e0.x * FIN;
        const unsigned short* x1 = xb + (size_t)e1.x * FIN;
        const unsigned short* x2 = xb + (size_t)e2.x * FIN;
        const unsigned short* x3 = xb + (size_t)e3.x * FIN;
        float v0 = __int_as_float(e0.y), v1 = __int_as_float(e1.y);
        float v2 = __int_as_float(e2.y), v3 = __int_as_float(e3.y);
        a0 += v0*b2f(x0[lane])    + v1*b2f(x1[lane])
            + v2*b2f(x2[lane])    + v3*b2f(x3[lane]);
        a1 += v0*b2f(x0[lane+32]) + v1*b2f(x1[lane+32])
            + v2*b2f(x2[lane+32]) + v3*b2f(x3[lane+32]);
        a2 += v0*b2f(x0[lane+64]) + v1*b2f(x1[lane+64])
            + v2*b2f(x2[lane+64]) + v3*b2f(x3[lane+64]);
    }
    for (; j < end; ++j) {
        int2 e = epack[j];
        float v = __int_as_float(e.y);
        const unsigned short* xr = xb + (size_t)e.x * FIN;
        a0 += v * b2f(xr[lane]);
        a1 += v * b2f(xr[lane + 32]);
        a2 += v * b2f(xr[lane + 64]);
    }
    float e = epsp[0];
    const unsigned short* xs = xb + (size_t)rid * FIN;
    a0 += e * b2f(xs[lane]);
    a1 += e * b2f(xs[lane + 32]);
    a2 += e * b2f(xs[lane + 64]);
    unsigned short* ar = aggb + (size_t)rid * FIN;
    ar[lane]      = f2b(a0);
    ar[lane + 32] = f2b(a1);
    ar[lane + 64] = f2b(a2);
}

// ---------------- GEMM1: h1 = agg @ W1 + b1 (bf16) + stats ----------------
// BM=64, BN=384 (full). B fully LDS-resident, A register-resident,
// NO barriers in the K-loop. 4 waves = 2M x 2N, wave tile 32x192.
#define G1_LDB 104
__global__ __launch_bounds__(256) void gemm1_mfma_kernel(
    const unsigned short* __restrict__ aggb, const unsigned short* __restrict__ W1T,
    const float* __restrict__ b1,
    unsigned short* __restrict__ h1, float* __restrict__ sum1,
    float* __restrict__ sq1)
{
    __shared__ short Bs[FHID * G1_LDB];   // 384 x 104 = 79.9 KB
    int tid = threadIdx.x;
    int m0 = blockIdx.x * 64;
    int lane = tid & 63;
    int w = tid >> 6, wr = w >> 1, wc = w & 1;
    int l15 = lane & 15, lk = (lane >> 4) * 8;

    // stage all of W1T: 384 rows x 12 vec8 = 4608 vec8, 18/thread, coalesced
    #pragma unroll
    for (int l = 0; l < 18; ++l) {
        int idx = tid + l * 256;
        int n = idx / 12, k8 = (idx - n * 12) * 8;
        *(short8v*)&Bs[n * G1_LDB + k8] =
            *(const short8v*)(W1T + (size_t)n * FIN + k8);
    }
    // A fragments: rows m0 + wr*32 + fm*16 + l15, all K (3 slices)
    short8v af[2][3];
    #pragma unroll
    for (int fm = 0; fm < 2; ++fm) {
        int gm = m0 + wr * 32 + fm * 16 + l15;
        #pragma unroll
        for (int ks = 0; ks < 3; ++ks)
            af[fm][ks] = (gm < NN)
                ? *(const short8v*)(aggb + (size_t)gm * FIN + ks * 32 + lk)
                : (short8v)(short)0;
    }
    __syncthreads();

    f32x4 acc[2][12];
    #pragma unroll
    for (int a = 0; a < 2; ++a)
        #pragma unroll
        for (int b = 0; b < 12; ++b) acc[a][b] = (f32x4)(0.f);

    #pragma unroll
    for (int ks = 0; ks < 3; ++ks) {
        #pragma unroll
        for (int fn = 0; fn < 12; ++fn) {
            short8v bf = *(short8v*)&Bs[(wc*192 + fn*16 + l15) * G1_LDB
                                        + ks*32 + lk];
            #pragma unroll
            for (int fm = 0; fm < 2; ++fm)
                acc[fm][fn] = __builtin_amdgcn_mfma_f32_16x16x32_bf16(
                    af[fm][ks], bf, acc[fm][fn], 0, 0, 0);
        }
    }

    // epilogue: bias, bf16 h1 store, column stats
    float cs[12], cq[12];
    #pragma unroll
    for (int fn = 0; fn < 12; ++fn) { cs[fn] = 0.f; cq[fn] = 0.f; }
    #pragma unroll
    for (int fm = 0; fm < 2; ++fm) {
        int mb = m0 + wr*32 + fm*16 + (lane >> 4) * 4;
        #pragma unroll
        for (int r = 0; r < 4; ++r) {
            int gm = mb + r;
            if (gm < NN) {
                #pragma unroll
                for (int fn = 0; fn < 12; ++fn) {
                    int c = wc*192 + fn*16 + l15;
                    float h = acc[fm][fn][r] + b1[c];
                    cs[fn] += h; cq[fn] += h * h;
                    h1[(size_t)gm * FHID + c] = f2b(h);
                }
            }
        }
    }
    #pragma unroll
    for (int fn = 0; fn < 12; ++fn) {
        cs[fn] += __shfl_xor(cs[fn], 16); cs[fn] += __shfl_xor(cs[fn], 32);
        cq[fn] += __shfl_xor(cq[fn], 16); cq[fn] += __shfl_xor(cq[fn], 32);
    }
    __syncthreads();                 // all Bs reads done; reuse for stats
    float* sS = (float*)Bs;          // [4 waves][192] sum, +768 sq
    if (lane < 16) {
        #pragma unroll
        for (int fn = 0; fn < 12; ++fn) {
            sS[w * 192 + fn * 16 + l15]       = cs[fn];
            sS[768 + w * 192 + fn * 16 + l15] = cq[fn];
        }
    }
    __syncthreads();
    for (int c = tid; c < FHID; c += 256) {
        int wcg = c / 192, lc = c - wcg * 192;
        float s = sS[wcg * 192 + lc] + sS[(2 + wcg) * 192 + lc];
        float q = sS[768 + wcg * 192 + lc] + sS[768 + (2 + wcg) * 192 + lc];
        atomicAdd(sum1 + c, s);
        atomicAdd(sq1 + c, q);
    }
}

// ---------------- BN1 + ELU in-place on h1 (folds bnparam) ----------------
__global__ __launch_bounds__(256) void bn1_elu_kernel(
    unsigned short* __restrict__ h1,
    const float* __restrict__ sum1, const float* __restrict__ sq1,
    const float* __restrict__ g1, const float* __restrict__ be1)
{
    __shared__ float sc[FHID], sh[FHID];
    int tid = threadIdx.x;
    for (int c = tid; c < FHID; c += 256) {
        float mean = sum1[c] * (1.f / NN);
        float var  = sq1[c] * (1.f / NN) - mean * mean;
        float s = g1[c] * rsqrtf(var + BN_EPS);
        sc[c] = s;
        sh[c] = be1[c] - mean * s;
    }
    __syncthreads();
    int r0 = blockIdx.x * 64;
    #pragma unroll
    for (int l = 0; l < 12; ++l) {
        int idx = tid + l * 256;
        int rl = idx / 48, k8 = (idx - rl * 48) * 8;
        int gm = r0 + rl;
        if (gm >= NN) continue;
        unsigned short* p = h1 + (size_t)gm * FHID + k8;
        short8v v = *(short8v*)p;
        #pragma unroll
        for (int j = 0; j < 8; ++j) {
            int k = k8 + j;
            float t = sc[k] * b2f((unsigned short)v[j]) + sh[k];
            float e = t > 0.f ? t : __expf(t) - 1.f;
            v[j] = (short)f2b(e);
        }
        *(short8v*)p = v;
    }
}

// ---------------- GEMM2: h2 = elu1 @ W2 + b2 (bf16 pre-act) + stats -------
// BM=64, BN=96 per block (grid y=2). B fully LDS-resident, A in regs,
// no barriers in K-loop. 4 waves = 2M x 2N, wave tile 32x48.
#define G2_LDB 392
__global__ __launch_bounds__(256) void gemm2_mfma_kernel(
    const unsigned short* __restrict__ h1, const unsigned short* __restrict__ W2T,
    const float* __restrict__ b2,
    unsigned short* __restrict__ h2b, float* __restrict__ sum2,
    float* __restrict__ sq2)
{
    __shared__ short Bs[96 * G2_LDB];   // 96 x 392 = 75.3 KB
    int tid = threadIdx.x;
    int m0 = blockIdx.x * 64;
    int n0 = blockIdx.y * 96;
    int lane = tid & 63;
    int w = tid >> 6, wr = w >> 1, wc = w & 1;
    int l15 = lane & 15, lk = (lane >> 4) * 8;

    // stage 96 rows x 48 vec8 = 4608 vec8, 18/thread, coalesced
    #pragma unroll
    for (int l = 0; l < 18; ++l) {
        int idx = tid + l * 256;
        int n = idx / 48, k8 = (idx - n * 48) * 8;
        *(short8v*)&Bs[n * G2_LDB + k8] =
            *(const short8v*)(W2T + (size_t)(n0 + n) * FHID + k8);
    }
    // A fragments: 2 m-frags x 12 k-slices, issued together (deep MLP)
    short8v af[2][12];
    #pragma unroll
    for (int fm = 0; fm < 2; ++fm) {
        int gm = m0 + wr * 32 + fm * 16 + l15;
        #pragma unroll
        for (int ks = 0; ks < 12; ++ks)
            af[fm][ks] = (gm < NN)
                ? *(const short8v*)(h1 + (size_t)gm * FHID + ks * 32 + lk)
                : (short8v)(short)0;
    }
    __syncthreads();

    f32x4 acc[2][3];
    #pragma unroll
    for (int a = 0; a < 2; ++a)
        #pragma unroll
        for (int b = 0; b < 3; ++b) acc[a][b] = (f32x4)(0.f);

    #pragma unroll
    for (int ks = 0; ks < 12; ++ks) {
        #pragma unroll
        for (int fn = 0; fn < 3; ++fn) {
            short8v bf = *(short8v*)&Bs[(wc*48 + fn*16 + l15) * G2_LDB
                                        + ks*32 + lk];
            #pragma unroll
            for (int fm = 0; fm < 2; ++fm)
                acc[fm][fn] = __builtin_amdgcn_mfma_f32_16x16x32_bf16(
                    af[fm][ks], bf, acc[fm][fn], 0, 0, 0);
        }
    }

    // epilogue: bias, bf16 pre-act store, column stats
    float cs[3], cq[3];
    #pragma unroll
    for (int fn = 0; fn < 3; ++fn) { cs[fn] = 0.f; cq[fn] = 0.f; }
    #pragma unroll
    for (int fm = 0; fm < 2; ++fm) {
        int mb = m0 + wr*32 + fm*16 + (lane >> 4) * 4;
        #pragma unroll
        for (int r = 0; r < 4; ++r) {
            int gm = mb + r;
            if (gm < NN) {
                #pragma unroll
                for (int fn = 0; fn < 3; ++fn) {
                    int c = n0 + wc*48 + fn*16 + l15;
                    float v = acc[fm][fn][r] + b2[c];
                    cs[fn] += v; cq[fn] += v * v;
                    h2b[(size_t)gm * FOUT + c] = f2b(v);
                }
            }
        }
    }
    #pragma unroll
    for (int fn = 0; fn < 3; ++fn) {
        cs[fn] += __shfl_xor(cs[fn], 16); cs[fn] += __shfl_xor(cs[fn], 32);
        cq[fn] += __shfl_xor(cq[fn], 16); cq[fn] += __shfl_xor(cq[fn], 32);
    }
    __syncthreads();
    float* sS = (float*)Bs;          // [4 waves][96] sum, +384 sq
    if (lane < 16) {
        #pragma unroll
        for (int fn = 0; fn < 3; ++fn) {
            sS[w * 96 + wc*48 + fn*16 + l15]       = cs[fn];
            sS[384 + w * 96 + wc*48 + fn*16 + l15] = cq[fn];
        }
    }
    __syncthreads();
    if (tid < 96) {
        int w1 = (tid >= 48) ? 1 : 0;
        float s = sS[w1 * 96 + tid] + sS[(2 + w1) * 96 + tid];
        float q = sS[384 + w1 * 96 + tid] + sS[384 + (2 + w1) * 96 + tid];
        atomicAdd(sum2 + n0 + tid, s);
        atomicAdd(sq2 + n0 + tid, q);
    }
}

// ---------------- BN2 + ELU: h2b (bf16) -> out (fp32), folds bnparam ------
__global__ __launch_bounds__(256) void bn2_elu_kernel(
    const unsigned short* __restrict__ h2b, float* __restrict__ out,
    const float* __restrict__ sum2, const float* __restrict__ sq2,
    const float* __restrict__ g2, const float* __restrict__ be2)
{
    __shared__ float sc[FOUT], sh[FOUT];
    int tid = threadIdx.x;
    if (tid < FOUT) {
        float mean = sum2[tid] * (1.f / NN);
        float var  = sq2[tid] * (1.f / NN) - mean * mean;
        float s = g2[tid] * rsqrtf(var + BN_EPS);
        sc[tid] = s;
        sh[tid] = be2[tid] - mean * s;
    }
    __syncthreads();
    int r0 = blockIdx.x * 64;
    #pragma unroll
    for (int l = 0; l < 12; ++l) {
        int idx = tid + l * 256;
        int rl = idx / 48, c4 = (idx - rl * 48) * 4;
        int gm = r0 + rl;
        if (gm >= NN) continue;
        short4v v = *(const short4v*)(h2b + (size_t)gm * FOUT + c4);
        float4 o;
        float t0 = sc[c4+0] * b2f((unsigned short)v.x) + sh[c4+0];
        float t1 = sc[c4+1] * b2f((unsigned short)v.y) + sh[c4+1];
        float t2 = sc[c4+2] * b2f((unsigned short)v.z) + sh[c4+2];
        float t3 = sc[c4+3] * b2f((unsigned short)v.w) + sh[c4+3];
        o.x = t0 > 0.f ? t0 : __expf(t0) - 1.f;
        o.y = t1 > 0.f ? t1 : __expf(t1) - 1.f;
        o.z = t2 > 0.f ? t2 : __expf(t2) - 1.f;
        o.w = t3 > 0.f ? t3 : __expf(t3) - 1.f;
        *(float4*)(out + (size_t)gm * FOUT + c4) = o;
    }
}

__global__ __launch_bounds__(256) void zero_out_kernel(float* out, int n) {
    int gid = blockIdx.x * 256 + threadIdx.x;
    if (gid < n) out[gid] = 0.f;
}

extern "C" void kernel_launch(void* const* d_in, const int* in_sizes, int n_in,
                              void* d_out, int out_size, void* d_ws, size_t ws_size,
                              hipStream_t stream) {
    const float* x    = (const float*)d_in[0];
    const float* val  = (const float*)d_in[1];
    const float* W1   = (const float*)d_in[2];
    const float* b1   = (const float*)d_in[3];
    const float* g1   = (const float*)d_in[4];
    const float* be1  = (const float*)d_in[5];
    const float* W2   = (const float*)d_in[6];
    const float* b2   = (const float*)d_in[7];
    const float* g2   = (const float*)d_in[8];
    const float* be2  = (const float*)d_in[9];
    const float* epsp = (const float*)d_in[10];
    const int* row    = (const int*)d_in[11];
    const int* col    = (const int*)d_in[12];
    float* out = (float*)d_out;

    // ws layout (float idx):
    //        0 sum1[384] | 384 sq1[384] | 768 sum2[192] | 960 sq2[192]
    //     1152 deg int[50000]        -> 51152
    //    51152 offs int[50001]       -> 101153
    //   101153 bsum int[256]         -> 101409
    //   101409 bcur int[391]         -> 101800 (pad 101808)
    //   101808 W1T ushort[36864]     -> 120240
    //   120240 W2T ushort[73728]     -> 157104
    //   157104 xb  ushort[4.8M]      -> 2557104
    //  2557104 aggb ushort[4.8M]     -> 4957104 ; ebin int2[800K] aliases
    //          (ebin dead before gather writes aggb)
    //  4957104 h1 bf16[19.2M]        -> 14557104 ; epack int2[800K] aliases
    //          (epack dead before gemm1 writes h1)
    // 14557104 h2b ushort[9.6M]      -> 19357104  (77.4 MB)
    const size_t need = (size_t)19357104 * sizeof(float);
    if (ws_size < need) {
        zero_out_kernel<<<(out_size + 255) / 256, 256, 0, stream>>>(out, out_size);
        return;
    }
    float* ws     = (float*)d_ws;
    float* sum1   = ws;
    float* sq1    = ws + 384;
    float* sum2   = ws + 768;
    float* sq2    = ws + 960;
    int*   deg    = (int*)(ws + 1152);
    int*   offs   = (int*)(ws + 51152);
    int*   bsum   = (int*)(ws + 101153);
    int*   bcur   = (int*)(ws + 101409);
    unsigned short* W1T  = (unsigned short*)(ws + 101808);
    unsigned short* W2T  = (unsigned short*)(ws + 120240);
    unsigned short* xb   = (unsigned short*)(ws + 157104);
    unsigned short* aggb = (unsigned short*)(ws + 2557104);
    int2*  ebin   = (int2*)(ws + 2557104);          // alias aggb (dead early)
    unsigned short* h1   = (unsigned short*)(ws + 4957104);
    int2*  epack  = (int2*)(ws + 4957104);          // alias h1 (dead early)
    unsigned short* h2b  = (unsigned short*)(ws + 14557104);

    // zero stats + deg (205 KB)
    hipMemsetAsync(d_ws, 0, 51152 * sizeof(float), stream);

    const int prep_items = FHID*FIN + FOUT*FHID + NN*FIN/4;
    prep_kernel<<<(prep_items + 255) / 256, 256, 0, stream>>>(
        W1, W2, x, W1T, W2T, xb);

    hist_kernel<<<(EE + 255) / 256, 256, 0, stream>>>(row, deg);
    scan_partial_kernel<<<NBLK_SCAN, 256, 0, stream>>>(deg, bsum);
    scan_tot_kernel<<<1, 256, 0, stream>>>(bsum, offs);
    scan_final_kernel<<<NBLK_SCAN, 256, 0, stream>>>(deg, bsum, offs, bcur);

    bucket_bin_kernel<<<NCHUNK, 256, 0, stream>>>(row, col, val, bcur, ebin);
    rebin_kernel<<<NBUCKET, 256, 0, stream>>>(offs, ebin, epack);
    gather_kernel<<<(NN + 7) / 8, 256, 0, stream>>>(xb, offs, epack, epsp, aggb);

    gemm1_mfma_kernel<<<(NN + 63) / 64, 256, 0, stream>>>(
        aggb, W1T, b1, h1, sum1, sq1);
    bn1_elu_kernel<<<(NN + 63) / 64, 256, 0, stream>>>(h1, sum1, sq1, g1, be1);

    dim3 grid2((NN + 63) / 64, 2, 1);
    gemm2_mfma_kernel<<<grid2, 256, 0, stream>>>(
        h1, W2T, b2, h2b, sum2, sq2);
    bn2_elu_kernel<<<(NN + 63) / 64, 256, 0, stream>>>(
        h2b, out, sum2, sq2, g2, be2);
}

// Round 9
// 284.939 us; speedup vs baseline: 1.0881x; 1.0881x over previous
//
#include <hip/hip_runtime.h>
#include <math.h>

#define NN 50000
#define EE 800000
#define FIN 96
#define FHID 384
#define FOUT 192
#define BN_EPS 1e-5f
#define NBLK_SCAN 196   // ceil(NN/256)
#define NBUCKET 391     // ceil(NN/128), bucket = row >> 7
#define NCHUNK 391      // ceil(EE/2048)

typedef short  short4v  __attribute__((ext_vector_type(4)));
typedef short  short8v  __attribute__((ext_vector_type(8)));
typedef float  f32x4    __attribute__((ext_vector_type(4)));

__device__ __forceinline__ unsigned short f2b(float f) {   // fp32 -> bf16 RNE
    unsigned u = __float_as_uint(f);
    unsigned r = u + 0x7FFFu + ((u >> 16) & 1u);
    return (unsigned short)(r >> 16);
}
__device__ __forceinline__ float b2f(unsigned short s) {
    return __uint_as_float((unsigned)s << 16);
}

// ---------------- prep: weights bf16+transpose, x -> bf16 -----------------
__global__ __launch_bounds__(256) void prep_kernel(
    const float* __restrict__ W1, const float* __restrict__ W2,
    const float* __restrict__ x,
    unsigned short* __restrict__ W1T, unsigned short* __restrict__ W2T,
    unsigned short* __restrict__ xb)
{
    int gid = blockIdx.x * 256 + threadIdx.x;
    if (gid < FHID * FIN) {                 // W1T[n][k] = W1[k][n]
        int n = gid / FIN, k = gid - n * FIN;
        W1T[gid] = f2b(W1[(size_t)k * FHID + n]);
        return;
    }
    int j = gid - FHID * FIN;
    if (j < FOUT * FHID) {                  // W2T[n][k] = W2[k][n]
        int n = j / FHID, k = j - n * FHID;
        W2T[j] = f2b(W2[(size_t)k * FOUT + n]);
        return;
    }
    int i4 = gid - FHID * FIN - FOUT * FHID;
    if (i4 < NN * FIN / 4) {
        float4 v = *(const float4*)(x + (size_t)i4 * 4);
        short4v s;
        s.x = f2b(v.x); s.y = f2b(v.y); s.z = f2b(v.z); s.w = f2b(v.w);
        *(short4v*)(xb + (size_t)i4 * 4) = s;
    }
}

// ---------------- row-level CSR: hist + scan ------------------------------
__global__ __launch_bounds__(256) void hist_kernel(
    const int* __restrict__ row, int* __restrict__ deg)
{
    int i = blockIdx.x * 256 + threadIdx.x;
    if (i < EE) atomicAdd(&deg[row[i]], 1);
}

__global__ __launch_bounds__(256) void scan_partial_kernel(
    const int* __restrict__ deg, int* __restrict__ bsum)
{
    __shared__ int s[256];
    int t = threadIdx.x;
    int i = blockIdx.x * 256 + t;
    s[t] = (i < NN) ? deg[i] : 0;
    __syncthreads();
    #pragma unroll
    for (int o = 128; o > 0; o >>= 1) {
        if (t < o) s[t] += s[t + o];
        __syncthreads();
    }
    if (t == 0) bsum[blockIdx.x] = s[0];
}

__global__ __launch_bounds__(256) void scan_tot_kernel(
    int* __restrict__ bsum, int* __restrict__ offsets)
{
    __shared__ int s[256];
    int t = threadIdx.x;
    int v = (t < NBLK_SCAN) ? bsum[t] : 0;
    s[t] = v;
    __syncthreads();
    for (int o = 1; o < 256; o <<= 1) {
        int add = (t >= o) ? s[t - o] : 0;
        __syncthreads();
        s[t] += add;
        __syncthreads();
    }
    if (t < NBLK_SCAN) bsum[t] = s[t] - v;
    if (t == 255) offsets[NN] = s[255];
}

// offs[i] = exclusive scan; also bcur[b] = offs[128b] for the bin pass
__global__ __launch_bounds__(256) void scan_final_kernel(
    const int* __restrict__ deg, const int* __restrict__ bsum,
    int* __restrict__ offsets, int* __restrict__ bcur)
{
    __shared__ int s[256];
    int t = threadIdx.x;
    int i = blockIdx.x * 256 + t;
    int v = (i < NN) ? deg[i] : 0;
    s[t] = v;
    __syncthreads();
    for (int o = 1; o < 256; o <<= 1) {
        int add = (t >= o) ? s[t - o] : 0;
        __syncthreads();
        s[t] += add;
        __syncthreads();
    }
    int excl = s[t] - v + bsum[blockIdx.x];
    if (i < NN) {
        offsets[i] = excl;
        if ((i & 127) == 0) bcur[i >> 7] = excl;
    }
}

// ---------------- pass 1: bin edges by bucket (coalesced-run writes) ------
__global__ __launch_bounds__(256) void bucket_bin_kernel(
    const int* __restrict__ row, const int* __restrict__ col,
    const float* __restrict__ val, int* __restrict__ bcur,
    int2* __restrict__ ebin)
{
    __shared__ int lh[NBUCKET];
    __shared__ int lg[NBUCKET];
    int tid = threadIdx.x;
    for (int i = tid; i < NBUCKET; i += 256) lh[i] = 0;
    __syncthreads();
    int base = blockIdx.x * 2048;
    int eb[8], er[8], ec[8], ev[8];
    #pragma unroll
    for (int j = 0; j < 8; ++j) {
        int e = base + j * 256 + tid;
        eb[j] = -1;
        if (e < EE) {
            int r = row[e];
            int b = r >> 7;
            eb[j] = b;
            er[j] = atomicAdd(&lh[b], 1);              // local rank
            ec[j] = col[e] | ((r & 127) << 17);        // col(17b) | rowlocal(7b)
            ev[j] = __float_as_int(val[e]);
        }
    }
    __syncthreads();
    for (int i = tid; i < NBUCKET; i += 256)
        if (lh[i]) lg[i] = atomicAdd(&bcur[i], lh[i]);
    __syncthreads();
    #pragma unroll
    for (int j = 0; j < 8; ++j) {
        if (eb[j] >= 0)
            ebin[lg[eb[j]] + er[j]] = make_int2(ec[j], ev[j]);
    }
}

// ---------------- pass 2: row-sort within bucket (16 KB window writes) ----
__global__ __launch_bounds__(256) void rebin_kernel(
    const int* __restrict__ offs, const int2* __restrict__ ebin,
    int2* __restrict__ epack)
{
    __shared__ int lcur[128];
    int b = blockIdx.x;
    int tid = threadIdx.x;
    int rbase = b * 128;
    if (tid < 128) {
        int r = rbase + tid;
        lcur[tid] = (r < NN) ? offs[r] : 0;
    }
    __syncthreads();
    int beg = offs[rbase];
    int end = offs[min(rbase + 128, NN)];
    for (int e = beg + tid; e < end; e += 256) {
        int2 ed = ebin[e];
        int rl = ed.x >> 17;
        int p = atomicAdd(&lcur[rl], 1);
        epack[p] = make_int2(ed.x & 0x1FFFF, ed.y);
    }
}

// ---------------- gather-aggregate (row CSR, bf16 x) -> bf16 agg ----------
__global__ __launch_bounds__(256) void gather_kernel(
    const unsigned short* __restrict__ xb, const int* __restrict__ offsets,
    const int2* __restrict__ epack, const float* __restrict__ epsp,
    unsigned short* __restrict__ aggb)
{
    int rid = blockIdx.x * 8 + (threadIdx.x >> 5);
    if (rid >= NN) return;
    int lane = threadIdx.x & 31;
    int beg = offsets[rid], end = offsets[rid + 1];
    float a0 = 0.f, a1 = 0.f, a2 = 0.f;
    int j = beg;
    for (; j + 4 <= end; j += 4) {
        int2 e0 = epack[j],   e1 = epack[j+1];
        int2 e2 = epack[j+2], e3 = epack[j+3];
        const unsigned short* x0 = xb + (size_t)e0.x * FIN;
        const unsigned short* x1 = xb + (size_t)e1.x * FIN;
        const unsigned short* x2 = xb + (size_t)e2.x * FIN;
        const unsigned short* x3 = xb + (size_t)e3.x * FIN;
        float v0 = __int_as_float(e0.y), v1 = __int_as_float(e1.y);
        float v2 = __int_as_float(e2.y), v3 = __int_as_float(e3.y);
        a0 += v0*b2f(x0[lane])    + v1*b2f(x1[lane])
            + v2*b2f(x2[lane])    + v3*b2f(x3[lane]);
        a1 += v0*b2f(x0[lane+32]) + v1*b2f(x1[lane+32])
            + v2*b2f(x2[lane+32]) + v3*b2f(x3[lane+32]);
        a2 += v0*b2f(x0[lane+64]) + v1*b2f(x1[lane+64])
            + v2*b2f(x2[lane+64]) + v3*b2f(x3[lane+64]);
    }
    for (; j < end; ++j) {
        int2 e = epack[j];
        float v = __int_as_float(e.y);
        const unsigned short* xr = xb + (size_t)e.x * FIN;
        a0 += v * b2f(xr[lane]);
        a1 += v * b2f(xr[lane + 32]);
        a2 += v * b2f(xr[lane + 64]);
    }
    float e = epsp[0];
    const unsigned short* xs = xb + (size_t)rid * FIN;
    a0 += e * b2f(xs[lane]);
    a1 += e * b2f(xs[lane + 32]);
    a2 += e * b2f(xs[lane + 64]);
    unsigned short* ar = aggb + (size_t)rid * FIN;
    ar[lane]      = f2b(a0);
    ar[lane + 32] = f2b(a1);
    ar[lane + 64] = f2b(a2);
}

// ---------------- GEMM1 (MFMA): h1 = agg @ W1 + b1, bf16 out + stats -----
// BM=128, BN=128, K=96 resident. 4 waves, wave tile 64x64 (4x4 frags).
// LDA=100 shorts: 50 dwords = 18 mod 32 -> <=2-way bank aliasing (free).
#define G1_LD 100
__global__ __launch_bounds__(256) void gemm1_mfma_kernel(
    const unsigned short* __restrict__ aggb, const unsigned short* __restrict__ W1T,
    const float* __restrict__ b1,
    unsigned short* __restrict__ h1, float* __restrict__ sum1,
    float* __restrict__ sq1)
{
    __shared__ short As[128 * G1_LD];   // [m][k] bf16, 25 KB
    __shared__ short Bs[128 * G1_LD];   // [n][k] bf16, 25 KB
    int tid = threadIdx.x;
    int m0 = blockIdx.x * 128;
    int n0 = blockIdx.y * 128;
    int lane = tid & 63;
    int w = tid >> 6, wr = w >> 1, wc = w & 1;
    int l15 = lane & 15, lk = (lane >> 4) * 8;

    for (int i8 = tid; i8 < 128 * 12; i8 += 256) {
        int m = i8 / 12;
        int k8 = (i8 - m * 12) * 8;
        int gm = m0 + m;
        short8v v = (short8v)(short)0;
        if (gm < NN) v = *(const short8v*)(aggb + (size_t)gm * FIN + k8);
        *(short8v*)&As[m * G1_LD + k8] = v;
    }
    for (int i8 = tid; i8 < 128 * 12; i8 += 256) {
        int n = i8 / 12;
        int k8 = (i8 - n * 12) * 8;
        *(short8v*)&Bs[n * G1_LD + k8] =
            *(const short8v*)(W1T + (size_t)(n0 + n) * FIN + k8);
    }
    __syncthreads();

    f32x4 acc[4][4];
    #pragma unroll
    for (int a = 0; a < 4; ++a)
        #pragma unroll
        for (int b = 0; b < 4; ++b) acc[a][b] = (f32x4)(0.f);

    #pragma unroll
    for (int ks = 0; ks < 3; ++ks) {
        int k0 = ks * 32;
        short8v af[4], bf[4];
        #pragma unroll
        for (int f = 0; f < 4; ++f)
            af[f] = *(short8v*)&As[(wr*64 + f*16 + l15) * G1_LD + k0 + lk];
        #pragma unroll
        for (int f = 0; f < 4; ++f)
            bf[f] = *(short8v*)&Bs[(wc*64 + f*16 + l15) * G1_LD + k0 + lk];
        #pragma unroll
        for (int fm = 0; fm < 4; ++fm)
            #pragma unroll
            for (int fn = 0; fn < 4; ++fn)
                acc[fm][fn] = __builtin_amdgcn_mfma_f32_16x16x32_bf16(
                    af[fm], bf[fn], acc[fm][fn], 0, 0, 0);
    }

    float bias[4], cs[4], cq[4];
    #pragma unroll
    for (int fn = 0; fn < 4; ++fn) {
        bias[fn] = b1[n0 + wc*64 + fn*16 + l15];
        cs[fn] = 0.f; cq[fn] = 0.f;
    }
    #pragma unroll
    for (int fm = 0; fm < 4; ++fm) {
        int mb = m0 + wr*64 + fm*16 + (lane >> 4) * 4;
        #pragma unroll
        for (int r = 0; r < 4; ++r) {
            int gm = mb + r;
            if (gm < NN) {
                #pragma unroll
                for (int fn = 0; fn < 4; ++fn) {
                    float h = acc[fm][fn][r] + bias[fn];
                    cs[fn] += h; cq[fn] += h * h;
                    h1[(size_t)gm * FHID + n0 + wc*64 + fn*16 + l15] = f2b(h);
                }
            }
        }
    }
    #pragma unroll
    for (int fn = 0; fn < 4; ++fn) {
        cs[fn] += __shfl_xor(cs[fn], 16); cs[fn] += __shfl_xor(cs[fn], 32);
        cq[fn] += __shfl_xor(cq[fn], 16); cq[fn] += __shfl_xor(cq[fn], 32);
    }
    __syncthreads();
    float* sS = (float*)As;          // [4 waves][64] sum, then [4][64] sq
    if (lane < 16) {
        #pragma unroll
        for (int fn = 0; fn < 4; ++fn) {
            sS[w * 64 + fn * 16 + l15]       = cs[fn];
            sS[256 + w * 64 + fn * 16 + l15] = cq[fn];
        }
    }
    __syncthreads();
    if (tid < 128) {
        float s = sS[tid] + sS[tid + 128];
        float q = sS[256 + tid] + sS[256 + tid + 128];
        atomicAdd(sum1 + n0 + tid, s);
        atomicAdd(sq1 + n0 + tid, q);
    }
}

// ---------------- GEMM2 (MFMA): h2b = elu(bn1(h1)) @ W2 + b2 (bf16) ------
// BM=64, BN=192(full), BK=64 x 6 phases, reg double-buffered staging.
// BN1 scale/shift computed per-block from raw stats (folds bnparam1).
// LD=76 shorts: 38 dwords = 6 mod 32 -> <=2-way bank aliasing (free).
#define G2_LD 76
__global__ __launch_bounds__(256) void gemm2_mfma_kernel(
    const unsigned short* __restrict__ h1, const unsigned short* __restrict__ W2T,
    const float* __restrict__ b2,
    const float* __restrict__ sum1, const float* __restrict__ sq1,
    const float* __restrict__ g1, const float* __restrict__ be1,
    unsigned short* __restrict__ h2b, float* __restrict__ sum2,
    float* __restrict__ sq2)
{
    __shared__ short As[64 * G2_LD];     // 9.7 KB
    __shared__ short Bs[192 * G2_LD];    // 29.2 KB
    __shared__ float sc[FHID], sh[FHID]; // 3 KB
    int tid = threadIdx.x;
    int m0 = blockIdx.x * 64;
    int lane = tid & 63;
    int w = tid >> 6, wr = w >> 1, wc = w & 1;
    int l15 = lane & 15, lk = (lane >> 4) * 8;

    // fold bnparam1: sc/sh from raw stats (2 cols/thread)
    for (int c = tid; c < FHID; c += 256) {
        float mean = sum1[c] * (1.f / NN);
        float var  = sq1[c] * (1.f / NN) - mean * mean;
        float s = g1[c] * rsqrtf(var + BN_EPS);
        sc[c] = s;
        sh[c] = be1[c] - mean * s;
    }

    short8v pa[2], pb[6];

    auto LOAD = [&](int k0) {
        #pragma unroll
        for (int l = 0; l < 2; ++l) {
            int idx = tid + l * 256;
            int am = idx >> 3, k8 = (idx & 7) * 8;
            int gm = m0 + am;
            pa[l] = (gm < NN)
                ? *(const short8v*)(h1 + (size_t)gm * FHID + k0 + k8)
                : (short8v)(short)0;
        }
        #pragma unroll
        for (int l = 0; l < 6; ++l) {
            int idx = tid + l * 256;
            int bn = idx >> 3, k8 = (idx & 7) * 8;
            pb[l] = *(const short8v*)(W2T + (size_t)bn * FHID + k0 + k8);
        }
    };
    auto WRITE = [&](int k0) {
        #pragma unroll
        for (int l = 0; l < 2; ++l) {
            int idx = tid + l * 256;
            int am = idx >> 3, k8 = (idx & 7) * 8;
            short8v v;
            #pragma unroll
            for (int j = 0; j < 8; ++j) {
                int k = k0 + k8 + j;
                float t = sc[k] * b2f((unsigned short)pa[l][j]) + sh[k];
                float e = t > 0.f ? t : __expf(t) - 1.f;
                v[j] = (short)f2b(e);
            }
            *(short8v*)&As[am * G2_LD + k8] = v;
        }
        #pragma unroll
        for (int l = 0; l < 6; ++l) {
            int idx = tid + l * 256;
            int bn = idx >> 3, k8 = (idx & 7) * 8;
            *(short8v*)&Bs[bn * G2_LD + k8] = pb[l];
        }
    };

    f32x4 acc[2][6];
    #pragma unroll
    for (int a = 0; a < 2; ++a)
        #pragma unroll
        for (int b = 0; b < 6; ++b) acc[a][b] = (f32x4)(0.f);

    LOAD(0);
    __syncthreads();        // sc/sh ready
    WRITE(0);
    __syncthreads();

    for (int t = 0; t < 6; ++t) {
        if (t < 5) LOAD((t + 1) * 64);          // prefetch next phase
        #pragma unroll
        for (int ks = 0; ks < 2; ++ks) {
            short8v af[2], bf[6];
            #pragma unroll
            for (int f = 0; f < 2; ++f)
                af[f] = *(short8v*)&As[(wr*32 + f*16 + l15) * G2_LD + ks*32 + lk];
            #pragma unroll
            for (int g = 0; g < 6; ++g)
                bf[g] = *(short8v*)&Bs[(wc*96 + g*16 + l15) * G2_LD + ks*32 + lk];
            #pragma unroll
            for (int fm = 0; fm < 2; ++fm)
                #pragma unroll
                for (int fn = 0; fn < 6; ++fn)
                    acc[fm][fn] = __builtin_amdgcn_mfma_f32_16x16x32_bf16(
                        af[fm], bf[fn], acc[fm][fn], 0, 0, 0);
        }
        __syncthreads();
        if (t < 5) {
            WRITE((t + 1) * 64);                // BN+ELU in regs, then LDS
            __syncthreads();
        }
    }

    // epilogue: bias, bf16 pre-act store, column stats
    float bias[6], cs[6], cq[6];
    #pragma unroll
    for (int fn = 0; fn < 6; ++fn) {
        bias[fn] = b2[wc*96 + fn*16 + l15];
        cs[fn] = 0.f; cq[fn] = 0.f;
    }
    #pragma unroll
    for (int fm = 0; fm < 2; ++fm) {
        int mb = m0 + wr*32 + fm*16 + (lane >> 4) * 4;
        #pragma unroll
        for (int r = 0; r < 4; ++r) {
            int gm = mb + r;
            if (gm < NN) {
                #pragma unroll
                for (int fn = 0; fn < 6; ++fn) {
                    float v = acc[fm][fn][r] + bias[fn];
                    cs[fn] += v; cq[fn] += v * v;
                    h2b[(size_t)gm * FOUT + wc*96 + fn*16 + l15] = f2b(v);
                }
            }
        }
    }
    #pragma unroll
    for (int fn = 0; fn < 6; ++fn) {
        cs[fn] += __shfl_xor(cs[fn], 16); cs[fn] += __shfl_xor(cs[fn], 32);
        cq[fn] += __shfl_xor(cq[fn], 16); cq[fn] += __shfl_xor(cq[fn], 32);
    }
    __syncthreads();
    float* sS = (float*)As;          // [4 waves][96] sum, then [4][96] sq
    if (lane < 16) {
        #pragma unroll
        for (int fn = 0; fn < 6; ++fn) {
            sS[w * 96 + fn * 16 + l15]       = cs[fn];
            sS[384 + w * 96 + fn * 16 + l15] = cq[fn];
        }
    }
    __syncthreads();
    if (tid < 192) {
        float s = sS[tid] + sS[192 + tid];
        float q = sS[384 + tid] + sS[384 + 192 + tid];
        atomicAdd(sum2 + tid, s);
        atomicAdd(sq2 + tid, q);
    }
}

// ---------------- BN2 + ELU: h2b (bf16) -> out (fp32), folds bnparam2 -----
__global__ __launch_bounds__(256) void bn2_elu_kernel(
    const unsigned short* __restrict__ h2b, float* __restrict__ out,
    const float* __restrict__ sum2, const float* __restrict__ sq2,
    const float* __restrict__ g2, const float* __restrict__ be2)
{
    __shared__ float sc[FOUT], sh[FOUT];
    int tid = threadIdx.x;
    if (tid < FOUT) {
        float mean = sum2[tid] * (1.f / NN);
        float var  = sq2[tid] * (1.f / NN) - mean * mean;
        float s = g2[tid] * rsqrtf(var + BN_EPS);
        sc[tid] = s;
        sh[tid] = be2[tid] - mean * s;
    }
    __syncthreads();
    int r0 = blockIdx.x * 64;
    #pragma unroll
    for (int l = 0; l < 12; ++l) {
        int idx = tid + l * 256;
        int rl = idx / 48, c4 = (idx - rl * 48) * 4;
        int gm = r0 + rl;
        if (gm >= NN) continue;
        short4v v = *(const short4v*)(h2b + (size_t)gm * FOUT + c4);
        float4 o;
        float t0 = sc[c4+0] * b2f((unsigned short)v.x) + sh[c4+0];
        float t1 = sc[c4+1] * b2f((unsigned short)v.y) + sh[c4+1];
        float t2 = sc[c4+2] * b2f((unsigned short)v.z) + sh[c4+2];
        float t3 = sc[c4+3] * b2f((unsigned short)v.w) + sh[c4+3];
        o.x = t0 > 0.f ? t0 : __expf(t0) - 1.f;
        o.y = t1 > 0.f ? t1 : __expf(t1) - 1.f;
        o.z = t2 > 0.f ? t2 : __expf(t2) - 1.f;
        o.w = t3 > 0.f ? t3 : __expf(t3) - 1.f;
        *(float4*)(out + (size_t)gm * FOUT + c4) = o;
    }
}

__global__ __launch_bounds__(256) void zero_out_kernel(float* out, int n) {
    int gid = blockIdx.x * 256 + threadIdx.x;
    if (gid < n) out[gid] = 0.f;
}

extern "C" void kernel_launch(void* const* d_in, const int* in_sizes, int n_in,
                              void* d_out, int out_size, void* d_ws, size_t ws_size,
                              hipStream_t stream) {
    const float* x    = (const float*)d_in[0];
    const float* val  = (const float*)d_in[1];
    const float* W1   = (const float*)d_in[2];
    const float* b1   = (const float*)d_in[3];
    const float* g1   = (const float*)d_in[4];
    const float* be1  = (const float*)d_in[5];
    const float* W2   = (const float*)d_in[6];
    const float* b2   = (const float*)d_in[7];
    const float* g2   = (const float*)d_in[8];
    const float* be2  = (const float*)d_in[9];
    const float* epsp = (const float*)d_in[10];
    const int* row    = (const int*)d_in[11];
    const int* col    = (const int*)d_in[12];
    float* out = (float*)d_out;

    // ws layout (float idx):
    //        0 sum1[384] | 384 sq1[384] | 768 sum2[192] | 960 sq2[192]
    //     1152 deg int[50000]        -> 51152
    //    51152 offs int[50001]       -> 101153
    //   101153 bsum int[256]         -> 101409
    //   101409 bcur int[391]         -> 101800 (pad 101808)
    //   101808 W1T ushort[36864]     -> 120240
    //   120240 W2T ushort[73728]     -> 157104
    //   157104 xb  ushort[4.8M]      -> 2557104
    //  2557104 aggb ushort[4.8M]     -> 4957104 ; ebin int2[800K] aliases
    //          (ebin dead before gather writes aggb)
    //  4957104 h1 bf16[19.2M]        -> 14557104 ; epack int2[800K] aliases
    //          (epack dead before gemm1 writes h1)
    // 14557104 h2b ushort[9.6M]      -> 19357104  (77.4 MB)
    const size_t need = (size_t)19357104 * sizeof(float);
    if (ws_size < need) {
        zero_out_kernel<<<(out_size + 255) / 256, 256, 0, stream>>>(out, out_size);
        return;
    }
    float* ws     = (float*)d_ws;
    float* sum1   = ws;
    float* sq1    = ws + 384;
    float* sum2   = ws + 768;
    float* sq2    = ws + 960;
    int*   deg    = (int*)(ws + 1152);
    int*   offs   = (int*)(ws + 51152);
    int*   bsum   = (int*)(ws + 101153);
    int*   bcur   = (int*)(ws + 101409);
    unsigned short* W1T  = (unsigned short*)(ws + 101808);
    unsigned short* W2T  = (unsigned short*)(ws + 120240);
    unsigned short* xb   = (unsigned short*)(ws + 157104);
    unsigned short* aggb = (unsigned short*)(ws + 2557104);
    int2*  ebin   = (int2*)(ws + 2557104);          // alias aggb (dead early)
    unsigned short* h1   = (unsigned short*)(ws + 4957104);
    int2*  epack  = (int2*)(ws + 4957104);          // alias h1 (dead early)
    unsigned short* h2b  = (unsigned short*)(ws + 14557104);

    // zero stats + deg (205 KB)
    hipMemsetAsync(d_ws, 0, 51152 * sizeof(float), stream);

    const int prep_items = FHID*FIN + FOUT*FHID + NN*FIN/4;
    prep_kernel<<<(prep_items + 255) / 256, 256, 0, stream>>>(
        W1, W2, x, W1T, W2T, xb);

    hist_kernel<<<(EE + 255) / 256, 256, 0, stream>>>(row, deg);
    scan_partial_kernel<<<NBLK_SCAN, 256, 0, stream>>>(deg, bsum);
    scan_tot_kernel<<<1, 256, 0, stream>>>(bsum, offs);
    scan_final_kernel<<<NBLK_SCAN, 256, 0, stream>>>(deg, bsum, offs, bcur);

    bucket_bin_kernel<<<NCHUNK, 256, 0, stream>>>(row, col, val, bcur, ebin);
    rebin_kernel<<<NBUCKET, 256, 0, stream>>>(offs, ebin, epack);
    gather_kernel<<<(NN + 7) / 8, 256, 0, stream>>>(xb, offs, epack, epsp, aggb);

    dim3 grid1((NN + 127) / 128, 3, 1);
    gemm1_mfma_kernel<<<grid1, 256, 0, stream>>>(aggb, W1T, b1, h1, sum1, sq1);

    gemm2_mfma_kernel<<<(NN + 63) / 64, 256, 0, stream>>>(
        h1, W2T, b2, sum1, sq1, g1, be1, h2b, sum2, sq2);

    bn2_elu_kernel<<<(NN + 63) / 64, 256, 0, stream>>>(
        h2b, out, sum2, sq2, g2, be2);
}

// Round 10
// 255.730 us; speedup vs baseline: 1.2123x; 1.1142x over previous
//
#include <hip/hip_runtime.h>
#include <math.h>

#define NN 50000
#define EE 800000
#define FIN 96
#define FHID 384
#define FOUT 192
#define BN_EPS 1e-5f
#define NBUCKET 391     // ceil(NN/128), bucket = row >> 7
#define NCHUNK 391      // ceil(EE/2048)

typedef short  short4v  __attribute__((ext_vector_type(4)));
typedef short  short8v  __attribute__((ext_vector_type(8)));
typedef float  f32x4    __attribute__((ext_vector_type(4)));

__device__ __forceinline__ unsigned short f2b(float f) {   // fp32 -> bf16 RNE
    unsigned u = __float_as_uint(f);
    unsigned r = u + 0x7FFFu + ((u >> 16) & 1u);
    return (unsigned short)(r >> 16);
}
__device__ __forceinline__ float b2f(unsigned short s) {
    return __uint_as_float((unsigned)s << 16);
}

// ---------------- prep: weights bf16+transpose, x -> bf16 -----------------
__global__ __launch_bounds__(256) void prep_kernel(
    const float* __restrict__ W1, const float* __restrict__ W2,
    const float* __restrict__ x,
    unsigned short* __restrict__ W1T, unsigned short* __restrict__ W2T,
    unsigned short* __restrict__ xb)
{
    int gid = blockIdx.x * 256 + threadIdx.x;
    if (gid < FHID * FIN) {                 // W1T[n][k] = W1[k][n]
        int n = gid / FIN, k = gid - n * FIN;
        W1T[gid] = f2b(W1[(size_t)k * FHID + n]);
        return;
    }
    int j = gid - FHID * FIN;
    if (j < FOUT * FHID) {                  // W2T[n][k] = W2[k][n]
        int n = j / FHID, k = j - n * FHID;
        W2T[j] = f2b(W2[(size_t)k * FOUT + n]);
        return;
    }
    int i4 = gid - FHID * FIN - FOUT * FHID;
    if (i4 < NN * FIN / 4) {
        float4 v = *(const float4*)(x + (size_t)i4 * 4);
        short4v s;
        s.x = f2b(v.x); s.y = f2b(v.y); s.z = f2b(v.z); s.w = f2b(v.w);
        *(short4v*)(xb + (size_t)i4 * 4) = s;
    }
}

// ---------------- bucket histogram (LDS-chunked) --------------------------
__global__ __launch_bounds__(256) void bucket_hist_kernel(
    const int* __restrict__ row, int* __restrict__ bcnt)
{
    __shared__ int lh[NBUCKET];
    int tid = threadIdx.x;
    for (int i = tid; i < NBUCKET; i += 256) lh[i] = 0;
    __syncthreads();
    int base = blockIdx.x * 2048;
    #pragma unroll
    for (int j = 0; j < 8; ++j) {
        int e = base + j * 256 + tid;
        if (e < EE) atomicAdd(&lh[row[e] >> 7], 1);
    }
    __syncthreads();
    for (int i = tid; i < NBUCKET; i += 256)
        if (lh[i]) atomicAdd(&bcnt[i], lh[i]);
}

// ---------------- bucket scan (1 block); also offs[NN] = EE ---------------
__global__ __launch_bounds__(512) void bucket_scan_kernel(
    const int* __restrict__ bcnt, int* __restrict__ bofs,
    int* __restrict__ bcur, int* __restrict__ offs)
{
    __shared__ int s[512];
    int t = threadIdx.x;
    int v = (t < NBUCKET) ? bcnt[t] : 0;
    s[t] = v;
    __syncthreads();
    for (int o = 1; o < 512; o <<= 1) {
        int add = (t >= o) ? s[t - o] : 0;
        __syncthreads();
        s[t] += add;
        __syncthreads();
    }
    if (t < NBUCKET) {
        int excl = s[t] - v;
        bofs[t] = excl;
        bcur[t] = excl;
        if (t == NBUCKET - 1) {
            bofs[NBUCKET] = s[t];
            offs[NN] = s[t];            // == EE
        }
    }
}

// ---------------- pass 1: bin edges by bucket (coalesced-run writes) ------
__global__ __launch_bounds__(256) void bucket_bin_kernel(
    const int* __restrict__ row, const int* __restrict__ col,
    const float* __restrict__ val, int* __restrict__ bcur,
    int2* __restrict__ ebin)
{
    __shared__ int lh[NBUCKET];
    __shared__ int lg[NBUCKET];
    int tid = threadIdx.x;
    for (int i = tid; i < NBUCKET; i += 256) lh[i] = 0;
    __syncthreads();
    int base = blockIdx.x * 2048;
    int eb[8], er[8], ec[8], ev[8];
    #pragma unroll
    for (int j = 0; j < 8; ++j) {
        int e = base + j * 256 + tid;
        eb[j] = -1;
        if (e < EE) {
            int r = row[e];
            int b = r >> 7;
            eb[j] = b;
            er[j] = atomicAdd(&lh[b], 1);              // local rank
            ec[j] = col[e] | ((r & 127) << 17);        // col(17b) | rowlocal(7b)
            ev[j] = __float_as_int(val[e]);
        }
    }
    __syncthreads();
    for (int i = tid; i < NBUCKET; i += 256)
        if (lh[i]) lg[i] = atomicAdd(&bcur[i], lh[i]);
    __syncthreads();
    #pragma unroll
    for (int j = 0; j < 8; ++j) {
        if (eb[j] >= 0)
            ebin[lg[eb[j]] + er[j]] = make_int2(ec[j], ev[j]);
    }
}

// ---------------- pass 2: row-sort within bucket; derives row offsets -----
__global__ __launch_bounds__(256) void rebin_kernel(
    const int* __restrict__ bofs, const int2* __restrict__ ebin,
    int2* __restrict__ epack, int* __restrict__ offs)
{
    __shared__ int scn[128];
    __shared__ int lcur[128];
    int b = blockIdx.x;
    int tid = threadIdx.x;
    int rbase = b * 128;
    int beg = bofs[b], end = bofs[b + 1];
    if (tid < 128) scn[tid] = 0;
    __syncthreads();
    for (int e = beg + tid; e < end; e += 256)
        atomicAdd(&scn[ebin[e].x >> 17], 1);
    __syncthreads();
    int v = (tid < 128) ? scn[tid] : 0;
    for (int o = 1; o < 128; o <<= 1) {          // Hillis-Steele inclusive
        int add = (tid < 128 && tid >= o) ? scn[tid - o] : 0;
        __syncthreads();
        if (tid < 128) scn[tid] += add;
        __syncthreads();
    }
    if (tid < 128) {
        int rofs = beg + scn[tid] - v;           // exclusive
        lcur[tid] = rofs;
        int r = rbase + tid;
        if (r < NN) offs[r] = rofs;
    }
    __syncthreads();
    for (int e = beg + tid; e < end; e += 256) {
        int2 ed = ebin[e];
        int rl = ed.x >> 17;
        int p = atomicAdd(&lcur[rl], 1);
        epack[p] = make_int2(ed.x & 0x1FFFF, ed.y);
    }
}

// ---------------- gather-aggregate (row CSR, bf16 x) -> bf16 agg ----------
__global__ __launch_bounds__(256) void gather_kernel(
    const unsigned short* __restrict__ xb, const int* __restrict__ offsets,
    const int2* __restrict__ epack, const float* __restrict__ epsp,
    unsigned short* __restrict__ aggb)
{
    int rid = blockIdx.x * 8 + (threadIdx.x >> 5);
    if (rid >= NN) return;
    int lane = threadIdx.x & 31;
    int beg = offsets[rid], end = offsets[rid + 1];
    float a0 = 0.f, a1 = 0.f, a2 = 0.f;
    int j = beg;
    for (; j + 4 <= end; j += 4) {
        int2 e0 = epack[j],   e1 = epack[j+1];
        int2 e2 = epack[j+2], e3 = epack[j+3];
        const unsigned short* x0 = xb + (size_t)e0.x * FIN;
        const unsigned short* x1 = xb + (size_t)e1.x * FIN;
        const unsigned short* x2 = xb + (size_t)e2.x * FIN;
        const unsigned short* x3 = xb + (size_t)e3.x * FIN;
        float v0 = __int_as_float(e0.y), v1 = __int_as_float(e1.y);
        float v2 = __int_as_float(e2.y), v3 = __int_as_float(e3.y);
        a0 += v0*b2f(x0[lane])    + v1*b2f(x1[lane])
            + v2*b2f(x2[lane])    + v3*b2f(x3[lane]);
        a1 += v0*b2f(x0[lane+32]) + v1*b2f(x1[lane+32])
            + v2*b2f(x2[lane+32]) + v3*b2f(x3[lane+32]);
        a2 += v0*b2f(x0[lane+64]) + v1*b2f(x1[lane+64])
            + v2*b2f(x2[lane+64]) + v3*b2f(x3[lane+64]);
    }
    for (; j < end; ++j) {
        int2 e = epack[j];
        float v = __int_as_float(e.y);
        const unsigned short* xr = xb + (size_t)e.x * FIN;
        a0 += v * b2f(xr[lane]);
        a1 += v * b2f(xr[lane + 32]);
        a2 += v * b2f(xr[lane + 64]);
    }
    float e = epsp[0];
    const unsigned short* xs = xb + (size_t)rid * FIN;
    a0 += e * b2f(xs[lane]);
    a1 += e * b2f(xs[lane + 32]);
    a2 += e * b2f(xs[lane + 64]);
    unsigned short* ar = aggb + (size_t)rid * FIN;
    ar[lane]      = f2b(a0);
    ar[lane + 32] = f2b(a1);
    ar[lane + 64] = f2b(a2);
}

// ---------------- GEMM1 (MFMA): h1 = agg @ W1 + b1, bf16 out + stats -----
// BM=128, BN=128, K=96 resident. 4 waves, wave tile 64x64 (4x4 frags).
// LD=100 shorts: 50 dwords = 18 mod 32 -> <=2-way bank aliasing (free).
#define G1_LD 100
__global__ __launch_bounds__(256) void gemm1_mfma_kernel(
    const unsigned short* __restrict__ aggb, const unsigned short* __restrict__ W1T,
    const float* __restrict__ b1,
    unsigned short* __restrict__ h1, float* __restrict__ sum1,
    float* __restrict__ sq1)
{
    __shared__ short As[128 * G1_LD];   // [m][k] bf16, 25 KB
    __shared__ short Bs[128 * G1_LD];   // [n][k] bf16, 25 KB
    int tid = threadIdx.x;
    int m0 = blockIdx.x * 128;
    int n0 = blockIdx.y * 128;
    int lane = tid & 63;
    int w = tid >> 6, wr = w >> 1, wc = w & 1;
    int l15 = lane & 15, lk = (lane >> 4) * 8;

    for (int i8 = tid; i8 < 128 * 12; i8 += 256) {
        int m = i8 / 12;
        int k8 = (i8 - m * 12) * 8;
        int gm = m0 + m;
        short8v v = (short8v)(short)0;
        if (gm < NN) v = *(const short8v*)(aggb + (size_t)gm * FIN + k8);
        *(short8v*)&As[m * G1_LD + k8] = v;
    }
    for (int i8 = tid; i8 < 128 * 12; i8 += 256) {
        int n = i8 / 12;
        int k8 = (i8 - n * 12) * 8;
        *(short8v*)&Bs[n * G1_LD + k8] =
            *(const short8v*)(W1T + (size_t)(n0 + n) * FIN + k8);
    }
    __syncthreads();

    f32x4 acc[4][4];
    #pragma unroll
    for (int a = 0; a < 4; ++a)
        #pragma unroll
        for (int b = 0; b < 4; ++b) acc[a][b] = (f32x4)(0.f);

    #pragma unroll
    for (int ks = 0; ks < 3; ++ks) {
        int k0 = ks * 32;
        short8v af[4], bf[4];
        #pragma unroll
        for (int f = 0; f < 4; ++f)
            af[f] = *(short8v*)&As[(wr*64 + f*16 + l15) * G1_LD + k0 + lk];
        #pragma unroll
        for (int f = 0; f < 4; ++f)
            bf[f] = *(short8v*)&Bs[(wc*64 + f*16 + l15) * G1_LD + k0 + lk];
        #pragma unroll
        for (int fm = 0; fm < 4; ++fm)
            #pragma unroll
            for (int fn = 0; fn < 4; ++fn)
                acc[fm][fn] = __builtin_amdgcn_mfma_f32_16x16x32_bf16(
                    af[fm], bf[fn], acc[fm][fn], 0, 0, 0);
    }

    float bias[4], cs[4], cq[4];
    #pragma unroll
    for (int fn = 0; fn < 4; ++fn) {
        bias[fn] = b1[n0 + wc*64 + fn*16 + l15];
        cs[fn] = 0.f; cq[fn] = 0.f;
    }
    #pragma unroll
    for (int fm = 0; fm < 4; ++fm) {
        int mb = m0 + wr*64 + fm*16 + (lane >> 4) * 4;
        #pragma unroll
        for (int r = 0; r < 4; ++r) {
            int gm = mb + r;
            if (gm < NN) {
                #pragma unroll
                for (int fn = 0; fn < 4; ++fn) {
                    float h = acc[fm][fn][r] + bias[fn];
                    cs[fn] += h; cq[fn] += h * h;
                    h1[(size_t)gm * FHID + n0 + wc*64 + fn*16 + l15] = f2b(h);
                }
            }
        }
    }
    #pragma unroll
    for (int fn = 0; fn < 4; ++fn) {
        cs[fn] += __shfl_xor(cs[fn], 16); cs[fn] += __shfl_xor(cs[fn], 32);
        cq[fn] += __shfl_xor(cq[fn], 16); cq[fn] += __shfl_xor(cq[fn], 32);
    }
    __syncthreads();
    float* sS = (float*)As;          // [4 waves][64] sum, then [4][64] sq
    if (lane < 16) {
        #pragma unroll
        for (int fn = 0; fn < 4; ++fn) {
            sS[w * 64 + fn * 16 + l15]       = cs[fn];
            sS[256 + w * 64 + fn * 16 + l15] = cq[fn];
        }
    }
    __syncthreads();
    if (tid < 128) {
        float s = sS[tid] + sS[tid + 128];
        float q = sS[256 + tid] + sS[256 + tid + 128];
        atomicAdd(sum1 + n0 + tid, s);
        atomicAdd(sq1 + n0 + tid, q);
    }
}

// ---------------- GEMM2 (MFMA): h2b = elu(bn1(h1)) @ W2 + b2 (bf16) ------
// BM=64, BN=192(full), BK=64 x 6 phases. 2-deep register pipeline:
// LOAD(t+2) issued at phase t; WRITE(t+1) consumes loads a full phase old.
// LD=76 shorts: 38 dwords = 6 mod 32 -> <=2-way bank aliasing (free).
#define G2_LD 76
__global__ __launch_bounds__(256) void gemm2_mfma_kernel(
    const unsigned short* __restrict__ h1, const unsigned short* __restrict__ W2T,
    const float* __restrict__ b2,
    const float* __restrict__ sum1, const float* __restrict__ sq1,
    const float* __restrict__ g1, const float* __restrict__ be1,
    unsigned short* __restrict__ h2b, float* __restrict__ sum2,
    float* __restrict__ sq2)
{
    __shared__ short As[64 * G2_LD];     // 9.7 KB
    __shared__ short Bs[192 * G2_LD];    // 29.2 KB
    __shared__ float sc[FHID], sh[FHID]; // 3 KB
    int tid = threadIdx.x;
    int m0 = blockIdx.x * 64;
    int lane = tid & 63;
    int w = tid >> 6, wr = w >> 1, wc = w & 1;
    int l15 = lane & 15, lk = (lane >> 4) * 8;

    // fold bnparam1: sc/sh from raw stats
    for (int c = tid; c < FHID; c += 256) {
        float mean = sum1[c] * (1.f / NN);
        float var  = sq1[c] * (1.f / NN) - mean * mean;
        float s = g1[c] * rsqrtf(var + BN_EPS);
        sc[c] = s;
        sh[c] = be1[c] - mean * s;
    }

    // two named register buffer sets (static indexing only — no scratch)
    short8v pa0[2], pb0[6], pa1[2], pb1[6];

    const int aM  = tid >> 3;              // A row (2 slots: +0, +32)
    const int aK8 = (tid & 7) * 8;
    const int bN  = tid >> 3;              // B row (6 slots: +0..+160, step 32)
    const int bK8 = (tid & 7) * 8;

    auto LOAD0 = [&](int k0) {
        #pragma unroll
        for (int l = 0; l < 2; ++l) {
            int gm = m0 + aM + l * 32;
            pa0[l] = (gm < NN)
                ? *(const short8v*)(h1 + (size_t)gm * FHID + k0 + aK8)
                : (short8v)(short)0;
        }
        #pragma unroll
        for (int l = 0; l < 6; ++l)
            pb0[l] = *(const short8v*)(W2T + (size_t)(bN + l*32) * FHID + k0 + bK8);
    };
    auto LOAD1 = [&](int k0) {
        #pragma unroll
        for (int l = 0; l < 2; ++l) {
            int gm = m0 + aM + l * 32;
            pa1[l] = (gm < NN)
                ? *(const short8v*)(h1 + (size_t)gm * FHID + k0 + aK8)
                : (short8v)(short)0;
        }
        #pragma unroll
        for (int l = 0; l < 6; ++l)
            pb1[l] = *(const short8v*)(W2T + (size_t)(bN + l*32) * FHID + k0 + bK8);
    };
    auto WRITE0 = [&](int k0) {
        #pragma unroll
        for (int l = 0; l < 2; ++l) {
            short8v v;
            #pragma unroll
            for (int j = 0; j < 8; ++j) {
                int k = k0 + aK8 + j;
                float t = sc[k] * b2f((unsigned short)pa0[l][j]) + sh[k];
                float e = t > 0.f ? t : __expf(t) - 1.f;
                v[j] = (short)f2b(e);
            }
            *(short8v*)&As[(aM + l*32) * G2_LD + aK8] = v;
        }
        #pragma unroll
        for (int l = 0; l < 6; ++l)
            *(short8v*)&Bs[(bN + l*32) * G2_LD + bK8] = pb0[l];
    };
    auto WRITE1 = [&](int k0) {
        #pragma unroll
        for (int l = 0; l < 2; ++l) {
            short8v v;
            #pragma unroll
            for (int j = 0; j < 8; ++j) {
                int k = k0 + aK8 + j;
                float t = sc[k] * b2f((unsigned short)pa1[l][j]) + sh[k];
                float e = t > 0.f ? t : __expf(t) - 1.f;
                v[j] = (short)f2b(e);
            }
            *(short8v*)&As[(aM + l*32) * G2_LD + aK8] = v;
        }
        #pragma unroll
        for (int l = 0; l < 6; ++l)
            *(short8v*)&Bs[(bN + l*32) * G2_LD + bK8] = pb1[l];
    };

    f32x4 acc[2][6];
    #pragma unroll
    for (int a = 0; a < 2; ++a)
        #pragma unroll
        for (int b = 0; b < 6; ++b) acc[a][b] = (f32x4)(0.f);

    auto COMPUTE = [&]() {
        __builtin_amdgcn_s_setprio(1);
        #pragma unroll
        for (int ks = 0; ks < 2; ++ks) {
            short8v af[2], bf[6];
            #pragma unroll
            for (int f = 0; f < 2; ++f)
                af[f] = *(short8v*)&As[(wr*32 + f*16 + l15) * G2_LD + ks*32 + lk];
            #pragma unroll
            for (int g = 0; g < 6; ++g)
                bf[g] = *(short8v*)&Bs[(wc*96 + g*16 + l15) * G2_LD + ks*32 + lk];
            #pragma unroll
            for (int fm = 0; fm < 2; ++fm)
                #pragma unroll
                for (int fn = 0; fn < 6; ++fn)
                    acc[fm][fn] = __builtin_amdgcn_mfma_f32_16x16x32_bf16(
                        af[fm], bf[fn], acc[fm][fn], 0, 0, 0);
        }
        __builtin_amdgcn_s_setprio(0);
    };

    // ---- fully static 6-phase schedule, 2-deep prefetch ----
    LOAD0(0);                       // ph0 -> r0
    LOAD1(64);                      // ph1 -> r1
    __syncthreads();                // sc/sh ready
    WRITE0(0);                      // LDS = ph0
    __syncthreads();

    LOAD0(128); COMPUTE(); __syncthreads(); WRITE1(64);  __syncthreads();
    LOAD1(192); COMPUTE(); __syncthreads(); WRITE0(128); __syncthreads();
    LOAD0(256); COMPUTE(); __syncthreads(); WRITE1(192); __syncthreads();
    LOAD1(320); COMPUTE(); __syncthreads(); WRITE0(256); __syncthreads();
                COMPUTE(); __syncthreads(); WRITE1(320); __syncthreads();
                COMPUTE();

    // epilogue: bias, bf16 pre-act store, column stats
    float bias[6], cs[6], cq[6];
    #pragma unroll
    for (int fn = 0; fn < 6; ++fn) {
        bias[fn] = b2[wc*96 + fn*16 + l15];
        cs[fn] = 0.f; cq[fn] = 0.f;
    }
    #pragma unroll
    for (int fm = 0; fm < 2; ++fm) {
        int mb = m0 + wr*32 + fm*16 + (lane >> 4) * 4;
        #pragma unroll
        for (int r = 0; r < 4; ++r) {
            int gm = mb + r;
            if (gm < NN) {
                #pragma unroll
                for (int fn = 0; fn < 6; ++fn) {
                    float v = acc[fm][fn][r] + bias[fn];
                    cs[fn] += v; cq[fn] += v * v;
                    h2b[(size_t)gm * FOUT + wc*96 + fn*16 + l15] = f2b(v);
                }
            }
        }
    }
    #pragma unroll
    for (int fn = 0; fn < 6; ++fn) {
        cs[fn] += __shfl_xor(cs[fn], 16); cs[fn] += __shfl_xor(cs[fn], 32);
        cq[fn] += __shfl_xor(cq[fn], 16); cq[fn] += __shfl_xor(cq[fn], 32);
    }
    __syncthreads();
    float* sS = (float*)As;          // [4 waves][96] sum, then [4][96] sq
    if (lane < 16) {
        #pragma unroll
        for (int fn = 0; fn < 6; ++fn) {
            sS[w * 96 + fn * 16 + l15]       = cs[fn];
            sS[384 + w * 96 + fn * 16 + l15] = cq[fn];
        }
    }
    __syncthreads();
    if (tid < 192) {
        float s = sS[tid] + sS[192 + tid];
        float q = sS[384 + tid] + sS[384 + 192 + tid];
        atomicAdd(sum2 + tid, s);
        atomicAdd(sq2 + tid, q);
    }
}

// ---------------- BN2 + ELU: h2b (bf16) -> out (fp32), folds bnparam2 -----
__global__ __launch_bounds__(256) void bn2_elu_kernel(
    const unsigned short* __restrict__ h2b, float* __restrict__ out,
    const float* __restrict__ sum2, const float* __restrict__ sq2,
    const float* __restrict__ g2, const float* __restrict__ be2)
{
    __shared__ float sc[FOUT], sh[FOUT];
    int tid = threadIdx.x;
    if (tid < FOUT) {
        float mean = sum2[tid] * (1.f / NN);
        float var  = sq2[tid] * (1.f / NN) - mean * mean;
        float s = g2[tid] * rsqrtf(var + BN_EPS);
        sc[tid] = s;
        sh[tid] = be2[tid] - mean * s;
    }
    __syncthreads();
    int r0 = blockIdx.x * 64;
    #pragma unroll
    for (int l = 0; l < 12; ++l) {
        int idx = tid + l * 256;
        int rl = idx / 48, c4 = (idx - rl * 48) * 4;
        int gm = r0 + rl;
        if (gm >= NN) continue;
        short4v v = *(const short4v*)(h2b + (size_t)gm * FOUT + c4);
        float4 o;
        float t0 = sc[c4+0] * b2f((unsigned short)v.x) + sh[c4+0];
        float t1 = sc[c4+1] * b2f((unsigned short)v.y) + sh[c4+1];
        float t2 = sc[c4+2] * b2f((unsigned short)v.z) + sh[c4+2];
        float t3 = sc[c4+3] * b2f((unsigned short)v.w) + sh[c4+3];
        o.x = t0 > 0.f ? t0 : __expf(t0) - 1.f;
        o.y = t1 > 0.f ? t1 : __expf(t1) - 1.f;
        o.z = t2 > 0.f ? t2 : __expf(t2) - 1.f;
        o.w = t3 > 0.f ? t3 : __expf(t3) - 1.f;
        *(float4*)(out + (size_t)gm * FOUT + c4) = o;
    }
}

__global__ __launch_bounds__(256) void zero_out_kernel(float* out, int n) {
    int gid = blockIdx.x * 256 + threadIdx.x;
    if (gid < n) out[gid] = 0.f;
}

extern "C" void kernel_launch(void* const* d_in, const int* in_sizes, int n_in,
                              void* d_out, int out_size, void* d_ws, size_t ws_size,
                              hipStream_t stream) {
    const float* x    = (const float*)d_in[0];
    const float* val  = (const float*)d_in[1];
    const float* W1   = (const float*)d_in[2];
    const float* b1   = (const float*)d_in[3];
    const float* g1   = (const float*)d_in[4];
    const float* be1  = (const float*)d_in[5];
    const float* W2   = (const float*)d_in[6];
    const float* b2   = (const float*)d_in[7];
    const float* g2   = (const float*)d_in[8];
    const float* be2  = (const float*)d_in[9];
    const float* epsp = (const float*)d_in[10];
    const int* row    = (const int*)d_in[11];
    const int* col    = (const int*)d_in[12];
    float* out = (float*)d_out;

    // ws layout (float idx):
    //        0 sum1[384] | 384 sq1[384] | 768 sum2[192] | 960 sq2[192]
    //     1152 bcnt int[391]         -> 1543 (pad 1552)   [memset to here]
    //     1552 offs int[50001]       -> 51553
    //    51553 bofs int[392]         -> 51945
    //    51945 bcur int[391]         -> 52336
    //    52336 W1T ushort[36864]     -> 70768
    //    70768 W2T ushort[73728]     -> 107632
    //   107632 xb  ushort[4.8M]      -> 2507632
    //  2507632 aggb ushort[4.8M]     -> 4907632 ; ebin int2[800K] aliases
    //          (ebin dead after rebin, before gather writes aggb)
    //  4907632 h1 bf16[19.2M]        -> 14507632 ; epack int2[800K] aliases
    //          (epack dead before gemm1 writes h1)
    // 14507632 h2b ushort[9.6M]      -> 19307632  (77.2 MB)
    const size_t need = (size_t)19307632 * sizeof(float);
    if (ws_size < need) {
        zero_out_kernel<<<(out_size + 255) / 256, 256, 0, stream>>>(out, out_size);
        return;
    }
    float* ws     = (float*)d_ws;
    float* sum1   = ws;
    float* sq1    = ws + 384;
    float* sum2   = ws + 768;
    float* sq2    = ws + 960;
    int*   bcnt   = (int*)(ws + 1152);
    int*   offs   = (int*)(ws + 1552);
    int*   bofs   = (int*)(ws + 51553);
    int*   bcur   = (int*)(ws + 51945);
    unsigned short* W1T  = (unsigned short*)(ws + 52336);
    unsigned short* W2T  = (unsigned short*)(ws + 70768);
    unsigned short* xb   = (unsigned short*)(ws + 107632);
    unsigned short* aggb = (unsigned short*)(ws + 2507632);
    int2*  ebin   = (int2*)(ws + 2507632);          // alias aggb (dead early)
    unsigned short* h1   = (unsigned short*)(ws + 4907632);
    int2*  epack  = (int2*)(ws + 4907632);          // alias h1 (dead early)
    unsigned short* h2b  = (unsigned short*)(ws + 14507632);

    // zero stats + bcnt (6.2 KB)
    hipMemsetAsync(d_ws, 0, 1552 * sizeof(float), stream);

    const int prep_items = FHID*FIN + FOUT*FHID + NN*FIN/4;
    prep_kernel<<<(prep_items + 255) / 256, 256, 0, stream>>>(
        W1, W2, x, W1T, W2T, xb);

    bucket_hist_kernel<<<NCHUNK, 256, 0, stream>>>(row, bcnt);
    bucket_scan_kernel<<<1, 512, 0, stream>>>(bcnt, bofs, bcur, offs);
    bucket_bin_kernel<<<NCHUNK, 256, 0, stream>>>(row, col, val, bcur, ebin);
    rebin_kernel<<<NBUCKET, 256, 0, stream>>>(bofs, ebin, epack, offs);
    gather_kernel<<<(NN + 7) / 8, 256, 0, stream>>>(xb, offs, epack, epsp, aggb);

    dim3 grid1((NN + 127) / 128, 3, 1);
    gemm1_mfma_kernel<<<grid1, 256, 0, stream>>>(aggb, W1T, b1, h1, sum1, sq1);

    gemm2_mfma_kernel<<<(NN + 63) / 64, 256, 0, stream>>>(
        h1, W2T, b2, sum1, sq1, g1, be1, h2b, sum2, sq2);

    bn2_elu_kernel<<<(NN + 63) / 64, 256, 0, stream>>>(
        h2b, out, sum2, sq2, g2, be2);
}